// Round 11
// baseline (128.082 us; speedup 1.0000x reference)
//
#include <hip/hip_runtime.h>

#define NN 6144
#define SHIFTC (12.0f*1.4426950408889634f)
#define LOG2E 1.4426950408889634f

typedef float f32x4 __attribute__((ext_vector_type(4)));
typedef short short8 __attribute__((ext_vector_type(8)));
typedef int   i32x4 __attribute__((ext_vector_type(4)));

__device__ __forceinline__ float bf2f(unsigned short u){
  return __uint_as_float(((unsigned int)u)<<16);
}
__device__ __forceinline__ unsigned short f2bf(float f){
  unsigned int x = __float_as_uint(f);
  x += 0x7fffu + ((x>>16)&1u);   // RNE
  return (unsigned short)(x>>16);
}

// ---- kernel 1: WhT bf16 [256][NN] = (x @ W)^T ----
__global__ __launch_bounds__(256) void k_gemm(const float* __restrict__ x,
                                              const float* __restrict__ W,
                                              unsigned short* __restrict__ wht){
  __shared__ float sx[16*256];
  const int t = threadIdx.x;
  const int i0 = blockIdx.x * 16;
  {
    const int r = t >> 4, kc = t & 15;
    const float* src = x + (size_t)(i0 + r)*256 + kc*16;
    float* dst = sx + r*256 + kc*16;
#pragma unroll
    for (int q = 0; q < 4; ++q)
      *reinterpret_cast<f32x4*>(dst + 4*q) = *reinterpret_cast<const f32x4*>(src + 4*q);
  }
  __syncthreads();
  float acc[16];
#pragma unroll
  for (int r = 0; r < 16; ++r) acc[r] = 0.f;
  for (int k = 0; k < 256; k += 4) {
    const float w0 = W[(size_t)(k+0)*256 + t];
    const float w1 = W[(size_t)(k+1)*256 + t];
    const float w2 = W[(size_t)(k+2)*256 + t];
    const float w3 = W[(size_t)(k+3)*256 + t];
#pragma unroll
    for (int r = 0; r < 16; ++r) {
      f32x4 xv = *reinterpret_cast<const f32x4*>(sx + r*256 + k);
      acc[r] = fmaf(xv.x, w0, acc[r]);
      acc[r] = fmaf(xv.y, w1, acc[r]);
      acc[r] = fmaf(xv.z, w2, acc[r]);
      acc[r] = fmaf(xv.w, w3, acc[r]);
    }
  }
  alignas(16) unsigned short buf[16];
#pragma unroll
  for (int r = 0; r < 16; ++r) buf[r] = f2bf(acc[r]);
  unsigned short* dst = wht + (size_t)t*NN + i0;
  *reinterpret_cast<uint4*>(dst)     = *reinterpret_cast<const uint4*>(buf);
  *reinterpret_cast<uint4*>(dst + 8) = *reinterpret_cast<const uint4*>(buf + 8);
}

// ---- kernel 2: per-node score factors ----
__global__ __launch_bounds__(256) void k_f(const unsigned short* __restrict__ wht,
                                           const float* __restrict__ a,
                                           float* __restrict__ fs2,
                                           float* __restrict__ edp,
                                           float* __restrict__ edn){
  __shared__ unsigned short sw[256*64];
  const int t = threadIdx.x;
  const int i0 = blockIdx.x * 64;
  {
    const unsigned short* src = wht + (size_t)t*NN + i0;
    unsigned short* dst = sw + t*64;
#pragma unroll
    for (int q = 0; q < 8; ++q)
      *reinterpret_cast<uint4*>(dst + q*8) = *reinterpret_cast<const uint4*>(src + q*8);
  }
  __syncthreads();
  const int ii = t & 63, h = t >> 6;
  float s_ = 0.f, d_ = 0.f;
#pragma unroll 16
  for (int d = 0; d < 64; ++d) {
    const float v = bf2f(sw[(h*64 + d)*64 + ii]);
    s_ = fmaf(v, a[d],      s_);
    d_ = fmaf(v, a[64 + d], d_);
  }
  const float fs2v = s_ * LOG2E;
  const float fd2v = d_ * LOG2E;
  fs2[(size_t)h*NN + i0 + ii] = fs2v;
  edp[(size_t)h*NN + i0 + ii] = exp2f(fd2v - SHIFTC);
  edn[(size_t)h*NN + i0 + ii] = exp2f(0.2f * fd2v);
}

// ---- kernel 3: fused masked-softmax attention ----
// one head/block, dbuf LDS, 1 barrier/step, 2-deep adj prefetch, den via MFMA.
__global__ __launch_bounds__(256) void k_attn(const int* __restrict__ adj,
                                              const unsigned short* __restrict__ wht,
                                              const float* __restrict__ fs2,
                                              const float* __restrict__ edp,
                                              const float* __restrict__ edn,
                                              float* __restrict__ apart,
                                              float* __restrict__ lpart,
                                              int nsteps){   // nsteps is even
  __shared__ unsigned short swht[2][64*72];
  __shared__ unsigned int   smask[2][128];
  __shared__ float          sedp[2][64];
  __shared__ float          sedn[2][64];
  const int t  = threadIdx.x;
  const int w  = t >> 6, l = t & 63, lr = l & 15, hi = l >> 4;
  const int bid = blockIdx.x;
  const int h   = (bid >> 3) & 3;
  const int g   = (bid & 7) | ((bid >> 5) << 3);
  const int it  = g % 96;
  const int js  = g / 96;
  const int i0 = it * 64;
  const int jbase = js * nsteps * 64;
  const int i_row = i0 + w*16 + lr;

  const float fsv  = fs2[(size_t)h*NN + i_row];
  const float EiNh = exp2f(-0.8f*fsv - SHIFTC);

  f32x4 acc[4];
#pragma unroll
  for (int q = 0; q < 4; ++q) acc[q] = (f32x4){0.f,0.f,0.f,0.f};
  f32x4 acc_den = (f32x4){0.f,0.f,0.f,0.f};
  const short8 vones = { (short)0x3F80,(short)0x3F80,(short)0x3F80,(short)0x3F80,
                         (short)0x3F80,(short)0x3F80,(short)0x3F80,(short)0x3F80 };

  const int r_ = t >> 2, ch_ = t & 3;
  const int* asrc = adj + (size_t)(i0 + r_)*NN + jbase + ch_*16;
  const unsigned short* wsrc = wht + (size_t)(h*64 + r_)*NN + jbase + ch_*16;
  const float* pesrc = edp + (size_t)h*NN + jbase;
  const float* nesrc = edn + (size_t)h*NN + jbase;

  // commit a staged step (regs -> LDS buffer NXT)
  auto commit = [&](int nxt, i32x4 A0, i32x4 A1, i32x4 A2, i32x4 A3,
                    uint4 W0, uint4 W1, float PE, float NE) {
    unsigned int bits =
        ((unsigned)A0.x)       | (((unsigned)A0.y)<<1)  | (((unsigned)A0.z)<<2)  | (((unsigned)A0.w)<<3)  |
        (((unsigned)A1.x)<<4)  | (((unsigned)A1.y)<<5)  | (((unsigned)A1.z)<<6)  | (((unsigned)A1.w)<<7)  |
        (((unsigned)A2.x)<<8)  | (((unsigned)A2.y)<<9)  | (((unsigned)A2.z)<<10) | (((unsigned)A2.w)<<11) |
        (((unsigned)A3.x)<<12) | (((unsigned)A3.y)<<13) | (((unsigned)A3.z)<<14) | (((unsigned)A3.w)<<15);
    unsigned short* dst = &swht[nxt][r_*72 + ch_*16];
    *reinterpret_cast<uint4*>(dst)     = W0;
    *reinterpret_cast<uint4*>(dst + 8) = W1;
    reinterpret_cast<unsigned short*>(smask[nxt])[r_*4 + ch_] = (unsigned short)bits;
    if (t < 64)       sedp[nxt][t]      = PE;
    else if (t < 128) sedn[nxt][t - 64] = NE;
  };

  // compute one step from LDS buffer CUR
  auto compute_step = [&](int cur) {
    const unsigned int m0 = smask[cur][(w*16 + lr)*2 + 0];
    const unsigned int m1 = smask[cur][(w*16 + lr)*2 + 1];
    float maskf[16];
#pragma unroll
    for (int e = 0; e < 8; ++e) {
      maskf[e]     = (float)((m0 >> (8*hi + e)) & 1u);
      maskf[8 + e] = (float)((m1 >> (8*hi + e)) & 1u);
    }
    const f32x4 ep0 = *reinterpret_cast<const f32x4*>(&sedp[cur][8*hi + 0]);
    const f32x4 ep1 = *reinterpret_cast<const f32x4*>(&sedp[cur][8*hi + 4]);
    const f32x4 ep2 = *reinterpret_cast<const f32x4*>(&sedp[cur][32 + 8*hi + 0]);
    const f32x4 ep3 = *reinterpret_cast<const f32x4*>(&sedp[cur][32 + 8*hi + 4]);
    const f32x4 en0 = *reinterpret_cast<const f32x4*>(&sedn[cur][8*hi + 0]);
    const f32x4 en1 = *reinterpret_cast<const f32x4*>(&sedn[cur][8*hi + 4]);
    const f32x4 en2 = *reinterpret_cast<const f32x4*>(&sedn[cur][32 + 8*hi + 0]);
    const f32x4 en3 = *reinterpret_cast<const f32x4*>(&sedn[cur][32 + 8*hi + 4]);
    float p[16];
    // p = mask * max(edp_j, EiN_i*edn_j)  — exact LeakyReLU-softmax factorization
#pragma unroll
    for (int e = 0; e < 4; ++e) {
      p[e]      = maskf[e]      * fmaxf(ep0[e], EiNh * en0[e]);
      p[4 + e]  = maskf[4 + e]  * fmaxf(ep1[e], EiNh * en1[e]);
      p[8 + e]  = maskf[8 + e]  * fmaxf(ep2[e], EiNh * en2[e]);
      p[12 + e] = maskf[12 + e] * fmaxf(ep3[e], EiNh * en3[e]);
    }
    int4 aw0, aw1;
    asm("v_cvt_pk_bf16_f32 %0, %1, %2" : "=v"(aw0.x) : "v"(p[0]),  "v"(p[1]));
    asm("v_cvt_pk_bf16_f32 %0, %1, %2" : "=v"(aw0.y) : "v"(p[2]),  "v"(p[3]));
    asm("v_cvt_pk_bf16_f32 %0, %1, %2" : "=v"(aw0.z) : "v"(p[4]),  "v"(p[5]));
    asm("v_cvt_pk_bf16_f32 %0, %1, %2" : "=v"(aw0.w) : "v"(p[6]),  "v"(p[7]));
    asm("v_cvt_pk_bf16_f32 %0, %1, %2" : "=v"(aw1.x) : "v"(p[8]),  "v"(p[9]));
    asm("v_cvt_pk_bf16_f32 %0, %1, %2" : "=v"(aw1.y) : "v"(p[10]), "v"(p[11]));
    asm("v_cvt_pk_bf16_f32 %0, %1, %2" : "=v"(aw1.z) : "v"(p[12]), "v"(p[13]));
    asm("v_cvt_pk_bf16_f32 %0, %1, %2" : "=v"(aw1.w) : "v"(p[14]), "v"(p[15]));
    const short8 af0 = __builtin_bit_cast(short8, aw0);
    const short8 af1 = __builtin_bit_cast(short8, aw1);
    // denominator row-sum on the MFMA pipe (every output column identical)
    acc_den = __builtin_amdgcn_mfma_f32_16x16x32_bf16(af0, vones, acc_den, 0, 0, 0);
    acc_den = __builtin_amdgcn_mfma_f32_16x16x32_bf16(af1, vones, acc_den, 0, 0, 0);
#pragma unroll
    for (int nc = 0; nc < 4; ++nc) {
      const unsigned short* bp = &swht[cur][(nc*16 + lr)*72 + 8*hi];
      const short8 b0 = *reinterpret_cast<const short8*>(bp);
      const short8 b1 = *reinterpret_cast<const short8*>(bp + 32);
      acc[nc] = __builtin_amdgcn_mfma_f32_16x16x32_bf16(af0, b0, acc[nc], 0, 0, 0);
      acc[nc] = __builtin_amdgcn_mfma_f32_16x16x32_bf16(af1, b1, acc[nc], 0, 0, 0);
    }
  };

  // ---- prologue: stage step 0 into buf0; prefetch adj step 1 ----
  i32x4 ajA0, ajA1, ajA2, ajA3, ajB0, ajB1, ajB2, ajB3;
  {
    const i32x4 a0 = *reinterpret_cast<const i32x4*>(asrc + 0);
    const i32x4 a1 = *reinterpret_cast<const i32x4*>(asrc + 4);
    const i32x4 a2 = *reinterpret_cast<const i32x4*>(asrc + 8);
    const i32x4 a3 = *reinterpret_cast<const i32x4*>(asrc + 12);
    const uint4 w0 = *reinterpret_cast<const uint4*>(wsrc);
    const uint4 w1 = *reinterpret_cast<const uint4*>(wsrc + 8);
    const float pe = (t < 64) ? pesrc[t] : 0.f;
    const float ne = (t >= 64 && t < 128) ? nesrc[t - 64] : 0.f;
    commit(0, a0, a1, a2, a3, w0, w1, pe, ne);
  }
  if (nsteps > 1) {
    const int* an = asrc + 64;
    ajA0 = *reinterpret_cast<const i32x4*>(an + 0);
    ajA1 = *reinterpret_cast<const i32x4*>(an + 4);
    ajA2 = *reinterpret_cast<const i32x4*>(an + 8);
    ajA3 = *reinterpret_cast<const i32x4*>(an + 12);
  }
  __syncthreads();

  for (int st = 0; st < nsteps; st += 2) {
    // ======== step st  (buf0) ========
    if (st + 2 < nsteps) {
      const int* an = asrc + (st + 2)*64;
      ajB0 = *reinterpret_cast<const i32x4*>(an + 0);
      ajB1 = *reinterpret_cast<const i32x4*>(an + 4);
      ajB2 = *reinterpret_cast<const i32x4*>(an + 8);
      ajB3 = *reinterpret_cast<const i32x4*>(an + 12);
    }
    {
      const int o = (st + 1)*64;   // st+1 < nsteps always (nsteps even)
      const uint4 wv0 = *reinterpret_cast<const uint4*>(wsrc + o);
      const uint4 wv1 = *reinterpret_cast<const uint4*>(wsrc + o + 8);
      const float pe = (t < 64) ? pesrc[o + t] : 0.f;
      const float ne = (t >= 64 && t < 128) ? nesrc[o + t - 64] : 0.f;
      compute_step(0);
      commit(1, ajA0, ajA1, ajA2, ajA3, wv0, wv1, pe, ne);
    }
    __syncthreads();
    // ======== step st+1 (buf1) ========
    if (st + 3 < nsteps) {
      const int* an = asrc + (st + 3)*64;
      ajA0 = *reinterpret_cast<const i32x4*>(an + 0);
      ajA1 = *reinterpret_cast<const i32x4*>(an + 4);
      ajA2 = *reinterpret_cast<const i32x4*>(an + 8);
      ajA3 = *reinterpret_cast<const i32x4*>(an + 12);
    }
    if (st + 2 < nsteps) {
      const int o = (st + 2)*64;
      const uint4 wv0 = *reinterpret_cast<const uint4*>(wsrc + o);
      const uint4 wv1 = *reinterpret_cast<const uint4*>(wsrc + o + 8);
      const float pe = (t < 64) ? pesrc[o + t] : 0.f;
      const float ne = (t >= 64 && t < 128) ? nesrc[o + t - 64] : 0.f;
      compute_step(1);
      commit(0, ajB0, ajB1, ajB2, ajB3, wv0, wv1, pe, ne);
    } else {
      compute_step(1);
    }
    __syncthreads();
  }

  // denominator: acc_den[rg] = row-sum for row i0 + w*16 + 4*hi + rg (all cols equal)
  if (lr == 0) {
#pragma unroll
    for (int rg = 0; rg < 4; ++rg)
      lpart[((size_t)js*4 + h)*NN + i0 + w*16 + 4*hi + rg] = acc_den[rg];
  }
  // C/D layout: col = lane&15, row = 4*(lane>>4)+reg   [m89-verified]
#pragma unroll
  for (int nc = 0; nc < 4; ++nc)
#pragma unroll
    for (int rg = 0; rg < 4; ++rg) {
      const int irow = i0 + w*16 + 4*hi + rg;
      const int col  = h*64 + nc*16 + lr;
      apart[((size_t)js*NN + irow)*256 + col] = acc[nc][rg];
    }
}

// ---- kernel 4: combine partials ----
__global__ __launch_bounds__(256) void k_comb(const float* __restrict__ apart,
                                              const float* __restrict__ lpart,
                                              float* __restrict__ out,
                                              int jsplit){
  const int idx = blockIdx.x * 256 + threadIdx.x;
  const int i = idx >> 8, c = idx & 255, h = c >> 6;
  float num = 0.f, den = 0.f;
  for (int s = 0; s < jsplit; ++s) {
    num += apart[((size_t)s*NN + i)*256 + c];
    den += lpart[((size_t)s*4 + h)*NN + i];
  }
  out[idx] = (den > 0.f) ? (num / den) : 0.f;
}

extern "C" void kernel_launch(void* const* d_in, const int* in_sizes, int n_in,
                              void* d_out, int out_size, void* d_ws, size_t ws_size,
                              hipStream_t stream) {
  const float* x   = (const float*)d_in[0];
  const int*   adj = (const int*)d_in[1];
  const float* W   = (const float*)d_in[2];
  const float* a   = (const float*)d_in[3];
  float* out = (float*)d_out;
  char* ws = (char*)d_ws;

  size_t off = 0;
  unsigned short* wht = (unsigned short*)(ws + off); off += (size_t)256*NN*2;
  float* fs2 = (float*)(ws + off); off += (size_t)4*NN*4;
  float* edp = (float*)(ws + off); off += (size_t)4*NN*4;
  float* edn = (float*)(ws + off); off += (size_t)4*NN*4;

  int jsplit = 8;
  while (jsplit > 1 &&
         off + (size_t)jsplit*4*NN*4 + (size_t)jsplit*NN*256*4 > ws_size)
    jsplit >>= 1;

  float* lpart = (float*)(ws + off); off += (size_t)jsplit*4*NN*4;
  float* apart = (float*)(ws + off);

  const int nsteps = NN / (jsplit * 64);   // 12/24/48/96 — always even

  k_gemm<<<dim3(NN/16), dim3(256), 0, stream>>>(x, W, wht);
  k_f   <<<dim3(NN/64), dim3(256), 0, stream>>>(wht, a, fs2, edp, edn);
  k_attn<<<dim3(4*(NN/64)*jsplit), dim3(256), 0, stream>>>(adj, wht, fs2, edp, edn, apart, lpart, nsteps);
  k_comb<<<dim3((out_size + 255)/256), dim3(256), 0, stream>>>(apart, lpart, out, jsplit);
}